// Round 15
// baseline (10759.981 us; speedup 1.0000x reference)
//
#include <hip/hip_runtime.h>
#include <math.h>

// Problem dims
#define TT 128
#define BB 512
#define EE 100
#define HH 256
#define G4 1024
#define NTAG 20

#define KW 384            // p3 K padded (356 -> 384)
#define KQ 256            // p1 K
#define KR 128            // p2 K padded (100 -> 128)
#define NW (1024*KW)      // 393216 elems per split
#define NQ (112*KQ)       // 28672
#define NR (256*KR)       // 32768

typedef short bf16x8 __attribute__((ext_vector_type(8)));
typedef float f32x4  __attribute__((ext_vector_type(4)));
#define MFMA16(a,b,c) __builtin_amdgcn_mfma_f32_16x16x32_bf16((a),(b),(c),0,0,0)
#define MM6(ACC,AH,AM,AL,BH,BM,BL) { \
    ACC = MFMA16(AH,BH,ACC); ACC = MFMA16(AH,BM,ACC); ACC = MFMA16(AM,BH,ACC); \
    ACC = MFMA16(AH,BL,ACC); ACC = MFMA16(AL,BH,ACC); ACC = MFMA16(AM,BM,ACC); }

__device__ __forceinline__ float sigm(float x){ return 1.f/(1.f+expf(-x)); }

// Exact-ish fp32 -> 3x bf16 split by truncation (24 mantissa bits captured).
__device__ __forceinline__ void split3(float v, unsigned short&a, unsigned short&b, unsigned short&c){
    unsigned u0 = __float_as_uint(v); a = (unsigned short)(u0>>16);
    float r1 = v - __uint_as_float(u0 & 0xFFFF0000u);
    unsigned u1 = __float_as_uint(r1); b = (unsigned short)(u1>>16);
    float r2 = r1 - __uint_as_float(u1 & 0xFFFF0000u);
    c = (unsigned short)(__float_as_uint(r2)>>16);
}

// ---------------------------------------------------------------------------
// prep8 (one direction): bf16x3-split, operand-layout-ready weight arrays.
// Ws[split][n][k] (k 0..99 = Wih^T, 100..355 = Whh^T, else 0), k-stride 384.
// Qs[split][e][k] = Q[k][e] (e<100 else 0), k-stride 256.
// Rs[split][j][k] = R[k][j] (k<100 else 0), k-stride 128.
// bP[n] = bih[n]+bhh[n].
// ---------------------------------------------------------------------------
__global__ void prep8(const float* __restrict__ Wih, const float* __restrict__ Whh,
                      const float* __restrict__ bih, const float* __restrict__ bhh,
                      const float* __restrict__ Q, const float* __restrict__ R,
                      unsigned short* __restrict__ Ws, unsigned short* __restrict__ Qs,
                      unsigned short* __restrict__ Rs, float* __restrict__ bP)
{
    int idx = blockIdx.x * blockDim.x + threadIdx.x;
    float v; unsigned short* dst; int str;
    if (idx < NW) {
        int n = idx / KW, k = idx - n * KW;
        v = (k < EE) ? Wih[n*EE + k] : (k < EE+HH) ? Whh[n*HH + (k-EE)] : 0.f;
        dst = Ws + idx; str = NW;
    } else if (idx < NW + NQ) {
        int i = idx - NW; int e = i >> 8, k = i & 255;
        v = (e < EE) ? Q[k*EE + e] : 0.f;
        dst = Qs + i; str = NQ;
    } else if (idx < NW + NQ + NR) {
        int i = idx - (NW + NQ); int j = i >> 7, k = i & 127;
        v = (k < EE) ? R[k*HH + j] : 0.f;
        dst = Rs + i; str = NR;
    } else if (idx < NW + NQ + NR + G4) {
        int n = idx - (NW + NQ + NR); bP[n] = bih[n] + bhh[n]; return;
    } else return;
    unsigned short a,b,c; split3(v,a,b,c);
    dst[0] = a; dst[str] = b; dst[2*str] = c;
}

// ---------------------------------------------------------------------------
// MFMA recurrence. 64 blocks (32 chunks x 2 dirs) x 512 thr, 16 rows/block.
// All GEMMs on matrix cores via bf16x3 (6 products = fp32-accurate).
// Wave w owns G-tiles {t : t%8==w} -> i/f/g/o of a column live in the SAME
// lane -> phase-4 cell update is fully register-local (no sG buffer).
// dirs alternate XCDs -> per-XCD W working set 2.36 MB, L2-resident.
// ---------------------------------------------------------------------------
__global__ __launch_bounds__(512, 1) void lstm11(
    const int* __restrict__ words, const float* __restrict__ embed,
    const unsigned short* __restrict__ Qsf, const unsigned short* __restrict__ Rsf,
    const unsigned short* __restrict__ Wsf, const float* __restrict__ bPf,
    const unsigned short* __restrict__ Qsb, const unsigned short* __restrict__ Rsb,
    const unsigned short* __restrict__ Wsb, const float* __restrict__ bPb,
    float* hfbuf, float* hbbuf)
{
    const int bid = blockIdx.x;
    const int dir = bid & 1;
    const int cb  = bid >> 1;        // 0..31
    const int b0  = cb * 16;
    const int tid = threadIdx.x;
    const int wv  = tid >> 6;        // wave 0..7
    const int ln  = tid & 63;
    const int nn  = ln & 15;         // operand row/col within tile
    const int gq  = ln >> 4;         // k-block group 0..3
    const int m4  = gq * 4;          // C/D row base

    const unsigned short* Qs = dir ? Qsb : Qsf;
    const unsigned short* Rs = dir ? Rsb : Rsf;
    const unsigned short* Ws = dir ? Wsb : Wsf;
    const float* bP = dir ? bPb : bPf;
    float* hout = dir ? hbbuf : hfbuf;

    __shared__ unsigned short sA[3][16][392];   // p3 A: [xm 0..99 | hm 100..355 | 0]
    __shared__ unsigned short sh3[3][16][264];  // h splits (p1 A), k 0..255
    __shared__ unsigned short sx3[3][16][136];  // xm splits (p2 A), k 0..127
    __shared__ float sH[16*256];                // h_prev fp32
    __shared__ int sWords[16*TT];

    {   // zero split arrays (pads MUST be 0); preload word ids
        unsigned* pa = (unsigned*)&sA[0][0][0];
        for (int i = tid; i < 9408; i += 512) pa[i] = 0;
        unsigned* pb = (unsigned*)&sh3[0][0][0];
        for (int i = tid; i < 6336; i += 512) pb[i] = 0;
        unsigned* pc = (unsigned*)&sx3[0][0][0];
        for (int i = tid; i < 3264; i += 512) pc[i] = 0;
        for (int i = tid; i < 16*TT; i += 512)
            sWords[i] = words[(b0 + (i >> 7)) * TT + (i & 127)];
    }

    float bq[8];                     // bias for acc q (col = wv*16+nn+128q)
    #pragma unroll
    for (int q = 0; q < 8; ++q) bq[q] = bP[wv*16 + nn + q*128];
    float cc[8];                     // cell state: [grp*4 + r]
    #pragma unroll
    for (int i = 0; i < 8; ++i) cc[i] = 0.f;

    const int koff = gq * 8;
    const f32x4 zv = {0.f, 0.f, 0.f, 0.f};
    __syncthreads();

    for (int s = 0; s < TT; ++s) {
        const int t = dir ? (TT-1-s) : s;

        // ---- phase 1: P = h@Q (MFMA); xm = 2*sig(P)*x -> sA/sx3 splits ----
        if (wv < 7) {
            const int e = wv*16 + nn;
            const bool ev = (e < EE);
            float xv0=0.f, xv1=0.f, xv2=0.f, xv3=0.f;
            if (ev) {
                xv0 = embed[(size_t)sWords[(m4+0)*TT + t]*EE + e];
                xv1 = embed[(size_t)sWords[(m4+1)*TT + t]*EE + e];
                xv2 = embed[(size_t)sWords[(m4+2)*TT + t]*EE + e];
                xv3 = embed[(size_t)sWords[(m4+3)*TT + t]*EE + e];
            }
            float pr0, pr1, pr2, pr3;
            if (s > 0) {
                f32x4 p = zv;
                const unsigned short* qb = Qs + (size_t)e * KQ;
                #pragma unroll
                for (int ks = 0; ks < 8; ++ks) {
                    const int ao = ks*32 + koff;
                    bf16x8 ah = *(const bf16x8*)&sh3[0][nn][ao];
                    bf16x8 am = *(const bf16x8*)&sh3[1][nn][ao];
                    bf16x8 al = *(const bf16x8*)&sh3[2][nn][ao];
                    bf16x8 bh = *(const bf16x8*)(qb + ao);
                    bf16x8 bm = *(const bf16x8*)(qb + NQ + ao);
                    bf16x8 bl = *(const bf16x8*)(qb + 2*NQ + ao);
                    MM6(p, ah, am, al, bh, bm, bl);
                }
                pr0 = 2.f*sigm(p[0])*xv0; pr1 = 2.f*sigm(p[1])*xv1;
                pr2 = 2.f*sigm(p[2])*xv2; pr3 = 2.f*sigm(p[3])*xv3;
            } else {   // h=0 -> 2*sig(0)=1 -> xm = x
                pr0 = xv0; pr1 = xv1; pr2 = xv2; pr3 = xv3;
            }
            if (ev) {
                unsigned short a,b,c;
                split3(pr0,a,b,c); sA[0][m4+0][e]=a; sA[1][m4+0][e]=b; sA[2][m4+0][e]=c;
                                   sx3[0][m4+0][e]=a; sx3[1][m4+0][e]=b; sx3[2][m4+0][e]=c;
                split3(pr1,a,b,c); sA[0][m4+1][e]=a; sA[1][m4+1][e]=b; sA[2][m4+1][e]=c;
                                   sx3[0][m4+1][e]=a; sx3[1][m4+1][e]=b; sx3[2][m4+1][e]=c;
                split3(pr2,a,b,c); sA[0][m4+2][e]=a; sA[1][m4+2][e]=b; sA[2][m4+2][e]=c;
                                   sx3[0][m4+2][e]=a; sx3[1][m4+2][e]=b; sx3[2][m4+2][e]=c;
                split3(pr3,a,b,c); sA[0][m4+3][e]=a; sA[1][m4+3][e]=b; sA[2][m4+3][e]=c;
                                   sx3[0][m4+3][e]=a; sx3[1][m4+3][e]=b; sx3[2][m4+3][e]=c;
            }
        }
        __syncthreads();

        // ---- phase 2: S = xm@R (MFMA); hm = 2*sig(S)*h_prev -> sA splits --
        if (s > 0) {
            f32x4 s0 = zv, s1 = zv;
            const int j0 = wv*16 + nn, j1 = j0 + 128;
            const unsigned short* rb0 = Rs + (size_t)j0 * KR;
            const unsigned short* rb1 = Rs + (size_t)j1 * KR;
            #pragma unroll
            for (int ks = 0; ks < 4; ++ks) {
                const int ao = ks*32 + koff;
                bf16x8 ah = *(const bf16x8*)&sx3[0][nn][ao];
                bf16x8 am = *(const bf16x8*)&sx3[1][nn][ao];
                bf16x8 al = *(const bf16x8*)&sx3[2][nn][ao];
                bf16x8 b0h = *(const bf16x8*)(rb0 + ao);
                bf16x8 b0m = *(const bf16x8*)(rb0 + NR + ao);
                bf16x8 b0l = *(const bf16x8*)(rb0 + 2*NR + ao);
                MM6(s0, ah, am, al, b0h, b0m, b0l);
                bf16x8 b1h = *(const bf16x8*)(rb1 + ao);
                bf16x8 b1m = *(const bf16x8*)(rb1 + NR + ao);
                bf16x8 b1l = *(const bf16x8*)(rb1 + 2*NR + ao);
                MM6(s1, ah, am, al, b1h, b1m, b1l);
            }
            #pragma unroll
            for (int r = 0; r < 4; ++r) {
                const int row = m4 + r;
                const float hm0 = 2.f*sigm(s0[r])*sH[row*256 + j0];
                const float hm1 = 2.f*sigm(s1[r])*sH[row*256 + j1];
                unsigned short a,b,c;
                split3(hm0,a,b,c); sA[0][row][100+j0]=a; sA[1][row][100+j0]=b; sA[2][row][100+j0]=c;
                split3(hm1,a,b,c); sA[0][row][100+j1]=a; sA[1][row][100+j1]=b; sA[2][row][100+j1]=c;
            }
        }
        __syncthreads();

        // ---- phase 3: G = [xm|hm]@W (MFMA, 8 tiles/wave) ------------------
        f32x4 acc[8];
        #pragma unroll
        for (int q = 0; q < 8; ++q) acc[q] = zv;
        const unsigned short* wb = Ws + (size_t)(wv*16 + nn) * KW;
        #pragma unroll
        for (int ks = 0; ks < 12; ++ks) {
            const int ao = ks*32 + koff;
            bf16x8 ah = *(const bf16x8*)&sA[0][nn][ao];
            bf16x8 am = *(const bf16x8*)&sA[1][nn][ao];
            bf16x8 al = *(const bf16x8*)&sA[2][nn][ao];
            #pragma unroll
            for (int q = 0; q < 8; ++q) {
                const unsigned short* wp = wb + (size_t)q * (128*KW) + ao;
                bf16x8 bh = *(const bf16x8*)(wp);
                bf16x8 bm = *(const bf16x8*)(wp + NW);
                bf16x8 bl = *(const bf16x8*)(wp + 2*NW);
                MM6(acc[q], ah, am, al, bh, bm, bl);
            }
        }

        // ---- phase 4: register-local cell update; h -> sH/sh3/hout --------
        #pragma unroll
        for (int grp = 0; grp < 2; ++grp) {
            const int j = wv*16 + nn + grp*128;
            #pragma unroll
            for (int r = 0; r < 4; ++r) {
                const int row = m4 + r;
                const float gi = acc[0+grp][r] + bq[0+grp];
                const float gf = acc[2+grp][r] + bq[2+grp];
                const float gg = acc[4+grp][r] + bq[4+grp];
                const float go = acc[6+grp][r] + bq[6+grp];
                const float cv = sigm(gf)*cc[grp*4+r] + sigm(gi)*tanhf(gg);
                cc[grp*4+r] = cv;
                const float hv = sigm(go)*tanhf(cv);
                sH[row*256 + j] = hv;
                unsigned short a,b,c;
                split3(hv,a,b,c);
                sh3[0][row][j] = a; sh3[1][row][j] = b; sh3[2][row][j] = c;
                __builtin_nontemporal_store(hv, &hout[((size_t)t*BB + b0 + row)*HH + j]);
            }
        }
        __syncthreads();
    }
}

// ---------------------------------------------------------------------------
// logits = [hf|hb] @ Wt^T + bt ; argmax (first index on ties) -> out[b][t]
// ---------------------------------------------------------------------------
__global__ __launch_bounds__(256) void logits_kernel(
    const float* __restrict__ hf, const float* __restrict__ hb,
    const float* __restrict__ Wt, const float* __restrict__ bt,
    int* __restrict__ out)
{
    __shared__ float sW[NTAG][2 * HH];
    __shared__ float sb[NTAG];
    const int tid = threadIdx.x;
    for (int i = tid; i < NTAG * 2 * HH; i += 256) (&sW[0][0])[i] = Wt[i];
    if (tid < NTAG) sb[tid] = bt[tid];
    __syncthreads();

    const int pos = blockIdx.x * 256 + tid;
    const int b  = pos & 511;
    const int t0 = pos >> 9;
    const int t1 = t0 + 64;

    float acc0[NTAG], acc1[NTAG];
    #pragma unroll
    for (int n = 0; n < NTAG; ++n) { acc0[n] = sb[n]; acc1[n] = sb[n]; }

    const float* f0 = hf + ((size_t)t0 * BB + b) * HH;
    const float* f1 = hf + ((size_t)t1 * BB + b) * HH;
    for (int k = 0; k < HH; k += 4) {
        const float4 a0 = *(const float4*)(f0 + k);
        const float4 a1 = *(const float4*)(f1 + k);
        #pragma unroll
        for (int n = 0; n < NTAG; ++n) {
            const float4 w = *(const float4*)&sW[n][k];
            acc0[n] += a0.x * w.x + a0.y * w.y + a0.z * w.z + a0.w * w.w;
            acc1[n] += a1.x * w.x + a1.y * w.y + a1.z * w.z + a1.w * w.w;
        }
    }
    const float* g0 = hb + ((size_t)t0 * BB + b) * HH;
    const float* g1 = hb + ((size_t)t1 * BB + b) * HH;
    for (int k = 0; k < HH; k += 4) {
        const float4 a0 = *(const float4*)(g0 + k);
        const float4 a1 = *(const float4*)(g1 + k);
        #pragma unroll
        for (int n = 0; n < NTAG; ++n) {
            const float4 w = *(const float4*)&sW[n][HH + k];
            acc0[n] += a0.x * w.x + a0.y * w.y + a0.z * w.z + a0.w * w.w;
            acc1[n] += a1.x * w.x + a1.y * w.y + a1.z * w.z + a1.w * w.w;
        }
    }

    float b0v = acc0[0]; int i0 = 0;
    float b1v = acc1[0]; int i1 = 0;
    #pragma unroll
    for (int n = 1; n < NTAG; ++n) {
        if (acc0[n] > b0v) { b0v = acc0[n]; i0 = n; }
        if (acc1[n] > b1v) { b1v = acc1[n]; i1 = n; }
    }
    out[b * TT + t0] = i0;
    out[b * TT + t1] = i1;
}

// ---------------------------------------------------------------------------
extern "C" void kernel_launch(void* const* d_in, const int* in_sizes, int n_in,
                              void* d_out, int out_size, void* d_ws, size_t ws_size,
                              hipStream_t stream)
{
    (void)in_sizes; (void)n_in; (void)out_size; (void)ws_size;

    const int*   words = (const int*)  d_in[0];
    const float* embd  = (const float*)d_in[5];
    const float* Wih_f = (const float*)d_in[6];
    const float* Whh_f = (const float*)d_in[7];
    const float* bih_f = (const float*)d_in[8];
    const float* bhh_f = (const float*)d_in[9];
    const float* Q_f   = (const float*)d_in[10];
    const float* R_f   = (const float*)d_in[11];
    const float* Wih_b = (const float*)d_in[12];
    const float* Whh_b = (const float*)d_in[13];
    const float* bih_b = (const float*)d_in[14];
    const float* bhh_b = (const float*)d_in[15];
    const float* Q_b   = (const float*)d_in[16];
    const float* R_b   = (const float*)d_in[17];
    const float* Wt    = (const float*)d_in[18];
    const float* bt    = (const float*)d_in[19];
    int* out = (int*)d_out;

    // workspace layout: hf, hb (fp32), biases, then bf16x3 split arrays (~134 MB)
    float* hf   = (float*)d_ws;
    float* hb   = hf + (size_t)TT * BB * HH;
    float* bP_f = hb + (size_t)TT * BB * HH;
    float* bP_b = bP_f + G4;
    unsigned short* Ws_f = (unsigned short*)(bP_b + G4);
    unsigned short* Qs_f = Ws_f + 3 * (size_t)NW;
    unsigned short* Rs_f = Qs_f + 3 * (size_t)NQ;
    unsigned short* Ws_b = Rs_f + 3 * (size_t)NR;
    unsigned short* Qs_b = Ws_b + 3 * (size_t)NW;
    unsigned short* Rs_b = Qs_b + 3 * (size_t)NQ;

    const int prep_grid = (NW + NQ + NR + G4 + 255) / 256;
    prep8<<<prep_grid, 256, 0, stream>>>(Wih_f, Whh_f, bih_f, bhh_f, Q_f, R_f,
                                         Ws_f, Qs_f, Rs_f, bP_f);
    prep8<<<prep_grid, 256, 0, stream>>>(Wih_b, Whh_b, bih_b, bhh_b, Q_b, R_b,
                                         Ws_b, Qs_b, Rs_b, bP_b);
    lstm11<<<64, 512, 0, stream>>>(words, embd, Qs_f, Rs_f, Ws_f, bP_f,
                                   Qs_b, Rs_b, Ws_b, bP_b, hf, hb);
    logits_kernel<<<128, 256, 0, stream>>>(hf, hb, Wt, bt, out);
}

// Round 16
// 9775.805 us; speedup vs baseline: 1.1007x; 1.1007x over previous
//
#include <hip/hip_runtime.h>
#include <math.h>

// Problem dims
#define TT 128
#define BB 512
#define EE 100
#define HH 256
#define G4 1024
#define NTAG 20

#define KW 384            // p3 K padded (356 -> 384)
#define KQ 256            // p1 K
#define KR 128            // p2 K padded (100 -> 128)
#define NW (1024*KW)      // 393216 elems per split
#define NQ (112*KQ)       // 28672
#define NR (256*KR)       // 32768

typedef short bf16x8 __attribute__((ext_vector_type(8)));
typedef float f32x4  __attribute__((ext_vector_type(4)));
#define MFMA16(a,b,c) __builtin_amdgcn_mfma_f32_16x16x32_bf16((a),(b),(c),0,0,0)
#define MM6(ACC,AH,AM,AL,BH,BM,BL) { \
    ACC = MFMA16(AH,BH,ACC); ACC = MFMA16(AH,BM,ACC); ACC = MFMA16(AM,BH,ACC); \
    ACC = MFMA16(AH,BL,ACC); ACC = MFMA16(AL,BH,ACC); ACC = MFMA16(AM,BM,ACC); }

__device__ __forceinline__ float sigm(float x){ return 1.f/(1.f+expf(-x)); }

// Exact-ish fp32 -> 3x bf16 split by truncation (24 mantissa bits captured).
__device__ __forceinline__ void split3(float v, unsigned short&a, unsigned short&b, unsigned short&c){
    unsigned u0 = __float_as_uint(v); a = (unsigned short)(u0>>16);
    float r1 = v - __uint_as_float(u0 & 0xFFFF0000u);
    unsigned u1 = __float_as_uint(r1); b = (unsigned short)(u1>>16);
    float r2 = r1 - __uint_as_float(u1 & 0xFFFF0000u);
    c = (unsigned short)(__float_as_uint(r2)>>16);
}

// ---------------------------------------------------------------------------
// prep8 (one direction): bf16x3-split weight arrays (unchanged from R15).
// ---------------------------------------------------------------------------
__global__ void prep8(const float* __restrict__ Wih, const float* __restrict__ Whh,
                      const float* __restrict__ bih, const float* __restrict__ bhh,
                      const float* __restrict__ Q, const float* __restrict__ R,
                      unsigned short* __restrict__ Ws, unsigned short* __restrict__ Qs,
                      unsigned short* __restrict__ Rs, float* __restrict__ bP)
{
    int idx = blockIdx.x * blockDim.x + threadIdx.x;
    float v; unsigned short* dst; int str;
    if (idx < NW) {
        int n = idx / KW, k = idx - n * KW;
        v = (k < EE) ? Wih[n*EE + k] : (k < EE+HH) ? Whh[n*HH + (k-EE)] : 0.f;
        dst = Ws + idx; str = NW;
    } else if (idx < NW + NQ) {
        int i = idx - NW; int e = i >> 8, k = i & 255;
        v = (e < EE) ? Q[k*EE + e] : 0.f;
        dst = Qs + i; str = NQ;
    } else if (idx < NW + NQ + NR) {
        int i = idx - (NW + NQ); int j = i >> 7, k = i & 127;
        v = (k < EE) ? R[k*HH + j] : 0.f;
        dst = Rs + i; str = NR;
    } else if (idx < NW + NQ + NR + G4) {
        int n = idx - (NW + NQ + NR); bP[n] = bih[n] + bhh[n]; return;
    } else return;
    unsigned short a,b,c; split3(v,a,b,c);
    dst[0] = a; dst[str] = b; dst[2*str] = c;
}

// ---- phase-3 schedule macros -----------------------------------------------
// LDWB(B, QB, AO): load W batch (tiles QB..QB+3, all 3 splits) into buffer B.
#define LDWB(B, QB, AO) { \
    WH##B##0 = *(const bf16x8*)(w##QB##0 + (AO));      WH##B##1 = *(const bf16x8*)(w##QB##1 + (AO)); \
    WH##B##2 = *(const bf16x8*)(w##QB##2 + (AO));      WH##B##3 = *(const bf16x8*)(w##QB##3 + (AO)); \
    WM##B##0 = *(const bf16x8*)(w##QB##0 + NW + (AO)); WM##B##1 = *(const bf16x8*)(w##QB##1 + NW + (AO)); \
    WM##B##2 = *(const bf16x8*)(w##QB##2 + NW + (AO)); WM##B##3 = *(const bf16x8*)(w##QB##3 + NW + (AO)); \
    WL##B##0 = *(const bf16x8*)(w##QB##0 + 2*NW + (AO)); WL##B##1 = *(const bf16x8*)(w##QB##1 + 2*NW + (AO)); \
    WL##B##2 = *(const bf16x8*)(w##QB##2 + 2*NW + (AO)); WL##B##3 = *(const bf16x8*)(w##QB##3 + 2*NW + (AO)); }

// MMG(B, QB): 24 MFMA product-major for tiles QB..QB+3 from buffer B.
// Adjacent MFMAs hit different accumulators (dep distance 4).
#define MMG(B, QB) { \
    acc[QB+0]=MFMA16(ah,WH##B##0,acc[QB+0]); acc[QB+1]=MFMA16(ah,WH##B##1,acc[QB+1]); \
    acc[QB+2]=MFMA16(ah,WH##B##2,acc[QB+2]); acc[QB+3]=MFMA16(ah,WH##B##3,acc[QB+3]); \
    acc[QB+0]=MFMA16(ah,WM##B##0,acc[QB+0]); acc[QB+1]=MFMA16(ah,WM##B##1,acc[QB+1]); \
    acc[QB+2]=MFMA16(ah,WM##B##2,acc[QB+2]); acc[QB+3]=MFMA16(ah,WM##B##3,acc[QB+3]); \
    acc[QB+0]=MFMA16(am,WH##B##0,acc[QB+0]); acc[QB+1]=MFMA16(am,WH##B##1,acc[QB+1]); \
    acc[QB+2]=MFMA16(am,WH##B##2,acc[QB+2]); acc[QB+3]=MFMA16(am,WH##B##3,acc[QB+3]); \
    acc[QB+0]=MFMA16(ah,WL##B##0,acc[QB+0]); acc[QB+1]=MFMA16(ah,WL##B##1,acc[QB+1]); \
    acc[QB+2]=MFMA16(ah,WL##B##2,acc[QB+2]); acc[QB+3]=MFMA16(ah,WL##B##3,acc[QB+3]); \
    acc[QB+0]=MFMA16(al,WH##B##0,acc[QB+0]); acc[QB+1]=MFMA16(al,WH##B##1,acc[QB+1]); \
    acc[QB+2]=MFMA16(al,WH##B##2,acc[QB+2]); acc[QB+3]=MFMA16(al,WH##B##3,acc[QB+3]); \
    acc[QB+0]=MFMA16(am,WM##B##0,acc[QB+0]); acc[QB+1]=MFMA16(am,WM##B##1,acc[QB+1]); \
    acc[QB+2]=MFMA16(am,WM##B##2,acc[QB+2]); acc[QB+3]=MFMA16(am,WM##B##3,acc[QB+3]); }

// ---------------------------------------------------------------------------
// MFMA recurrence (structure identical to R15/lstm11, which passed absmax 0).
// Phase 3 rescheduled: product-major MFMA + double-buffered W batches.
// ---------------------------------------------------------------------------
__global__ __launch_bounds__(512, 1) void lstm12(
    const int* __restrict__ words, const float* __restrict__ embed,
    const unsigned short* __restrict__ Qsf, const unsigned short* __restrict__ Rsf,
    const unsigned short* __restrict__ Wsf, const float* __restrict__ bPf,
    const unsigned short* __restrict__ Qsb, const unsigned short* __restrict__ Rsb,
    const unsigned short* __restrict__ Wsb, const float* __restrict__ bPb,
    float* hfbuf, float* hbbuf)
{
    const int bid = blockIdx.x;
    const int dir = bid & 1;
    const int cb  = bid >> 1;        // 0..31
    const int b0  = cb * 16;
    const int tid = threadIdx.x;
    const int wv  = tid >> 6;        // wave 0..7
    const int ln  = tid & 63;
    const int nn  = ln & 15;         // operand row/col within tile
    const int gq  = ln >> 4;         // k-block group 0..3
    const int m4  = gq * 4;          // C/D row base

    const unsigned short* Qs = dir ? Qsb : Qsf;
    const unsigned short* Rs = dir ? Rsb : Rsf;
    const unsigned short* Ws = dir ? Wsb : Wsf;
    const float* bP = dir ? bPb : bPf;
    float* hout = dir ? hbbuf : hfbuf;

    __shared__ unsigned short sA[3][16][392];   // p3 A: [xm 0..99 | hm 100..355 | 0]
    __shared__ unsigned short sh3[3][16][264];  // h splits (p1 A), k 0..255
    __shared__ unsigned short sx3[3][16][136];  // xm splits (p2 A), k 0..127
    __shared__ float sH[16*256];                // h_prev fp32
    __shared__ int sWords[16*TT];

    {   // zero split arrays (pads MUST be 0); preload word ids
        unsigned* pa = (unsigned*)&sA[0][0][0];
        for (int i = tid; i < 9408; i += 512) pa[i] = 0;
        unsigned* pb = (unsigned*)&sh3[0][0][0];
        for (int i = tid; i < 6336; i += 512) pb[i] = 0;
        unsigned* pc = (unsigned*)&sx3[0][0][0];
        for (int i = tid; i < 3264; i += 512) pc[i] = 0;
        for (int i = tid; i < 16*TT; i += 512)
            sWords[i] = words[(b0 + (i >> 7)) * TT + (i & 127)];
    }

    float bq[8];                     // bias for acc q (col = wv*16+nn+128q)
    #pragma unroll
    for (int q = 0; q < 8; ++q) bq[q] = bP[wv*16 + nn + q*128];
    float cc[8];                     // cell state: [grp*4 + r]
    #pragma unroll
    for (int i = 0; i < 8; ++i) cc[i] = 0.f;

    // hoisted W tile base pointers (col tile q -> base)
    const unsigned short* wb = Ws + (size_t)(wv*16 + nn) * KW;
    const unsigned short* w00 = wb;
    const unsigned short* w01 = wb + (size_t)1*(128*KW);
    const unsigned short* w02 = wb + (size_t)2*(128*KW);
    const unsigned short* w03 = wb + (size_t)3*(128*KW);
    const unsigned short* w40 = wb + (size_t)4*(128*KW);
    const unsigned short* w41 = wb + (size_t)5*(128*KW);
    const unsigned short* w42 = wb + (size_t)6*(128*KW);
    const unsigned short* w43 = wb + (size_t)7*(128*KW);

    const int koff = gq * 8;
    const f32x4 zv = {0.f, 0.f, 0.f, 0.f};
    __syncthreads();

    for (int s = 0; s < TT; ++s) {
        const int t = dir ? (TT-1-s) : s;

        // ---- phase 1: P = h@Q (MFMA); xm = 2*sig(P)*x -> sA/sx3 splits ----
        if (wv < 7) {
            const int e = wv*16 + nn;
            const bool ev = (e < EE);
            float xv0=0.f, xv1=0.f, xv2=0.f, xv3=0.f;
            if (ev) {
                xv0 = embed[(size_t)sWords[(m4+0)*TT + t]*EE + e];
                xv1 = embed[(size_t)sWords[(m4+1)*TT + t]*EE + e];
                xv2 = embed[(size_t)sWords[(m4+2)*TT + t]*EE + e];
                xv3 = embed[(size_t)sWords[(m4+3)*TT + t]*EE + e];
            }
            float pr0, pr1, pr2, pr3;
            if (s > 0) {
                f32x4 pa = zv, pb = zv;    // two parity chains
                const unsigned short* qb = Qs + (size_t)e * KQ;
                #pragma unroll
                for (int ks = 0; ks < 8; ks += 2) {
                    {
                        const int ao = ks*32 + koff;
                        bf16x8 ah = *(const bf16x8*)&sh3[0][nn][ao];
                        bf16x8 am = *(const bf16x8*)&sh3[1][nn][ao];
                        bf16x8 al = *(const bf16x8*)&sh3[2][nn][ao];
                        bf16x8 bh = *(const bf16x8*)(qb + ao);
                        bf16x8 bm = *(const bf16x8*)(qb + NQ + ao);
                        bf16x8 bl = *(const bf16x8*)(qb + 2*NQ + ao);
                        MM6(pa, ah, am, al, bh, bm, bl);
                    }
                    {
                        const int ao = (ks+1)*32 + koff;
                        bf16x8 ah = *(const bf16x8*)&sh3[0][nn][ao];
                        bf16x8 am = *(const bf16x8*)&sh3[1][nn][ao];
                        bf16x8 al = *(const bf16x8*)&sh3[2][nn][ao];
                        bf16x8 bh = *(const bf16x8*)(qb + ao);
                        bf16x8 bm = *(const bf16x8*)(qb + NQ + ao);
                        bf16x8 bl = *(const bf16x8*)(qb + 2*NQ + ao);
                        MM6(pb, ah, am, al, bh, bm, bl);
                    }
                }
                f32x4 p = pa + pb;
                pr0 = 2.f*sigm(p[0])*xv0; pr1 = 2.f*sigm(p[1])*xv1;
                pr2 = 2.f*sigm(p[2])*xv2; pr3 = 2.f*sigm(p[3])*xv3;
            } else {   // h=0 -> 2*sig(0)=1 -> xm = x
                pr0 = xv0; pr1 = xv1; pr2 = xv2; pr3 = xv3;
            }
            if (ev) {
                unsigned short a,b,c;
                split3(pr0,a,b,c); sA[0][m4+0][e]=a; sA[1][m4+0][e]=b; sA[2][m4+0][e]=c;
                                   sx3[0][m4+0][e]=a; sx3[1][m4+0][e]=b; sx3[2][m4+0][e]=c;
                split3(pr1,a,b,c); sA[0][m4+1][e]=a; sA[1][m4+1][e]=b; sA[2][m4+1][e]=c;
                                   sx3[0][m4+1][e]=a; sx3[1][m4+1][e]=b; sx3[2][m4+1][e]=c;
                split3(pr2,a,b,c); sA[0][m4+2][e]=a; sA[1][m4+2][e]=b; sA[2][m4+2][e]=c;
                                   sx3[0][m4+2][e]=a; sx3[1][m4+2][e]=b; sx3[2][m4+2][e]=c;
                split3(pr3,a,b,c); sA[0][m4+3][e]=a; sA[1][m4+3][e]=b; sA[2][m4+3][e]=c;
                                   sx3[0][m4+3][e]=a; sx3[1][m4+3][e]=b; sx3[2][m4+3][e]=c;
            }
        }
        __syncthreads();

        // ---- phase 2: S = xm@R (MFMA); hm = 2*sig(S)*h_prev -> sA splits --
        if (s > 0) {
            f32x4 s0 = zv, s1 = zv;
            const int j0 = wv*16 + nn, j1 = j0 + 128;
            const unsigned short* rb0 = Rs + (size_t)j0 * KR;
            const unsigned short* rb1 = Rs + (size_t)j1 * KR;
            #pragma unroll
            for (int ks = 0; ks < 4; ++ks) {
                const int ao = ks*32 + koff;
                bf16x8 ah = *(const bf16x8*)&sx3[0][nn][ao];
                bf16x8 am = *(const bf16x8*)&sx3[1][nn][ao];
                bf16x8 al = *(const bf16x8*)&sx3[2][nn][ao];
                bf16x8 b0h = *(const bf16x8*)(rb0 + ao);
                bf16x8 b0m = *(const bf16x8*)(rb0 + NR + ao);
                bf16x8 b0l = *(const bf16x8*)(rb0 + 2*NR + ao);
                MM6(s0, ah, am, al, b0h, b0m, b0l);
                bf16x8 b1h = *(const bf16x8*)(rb1 + ao);
                bf16x8 b1m = *(const bf16x8*)(rb1 + NR + ao);
                bf16x8 b1l = *(const bf16x8*)(rb1 + 2*NR + ao);
                MM6(s1, ah, am, al, b1h, b1m, b1l);
            }
            #pragma unroll
            for (int r = 0; r < 4; ++r) {
                const int row = m4 + r;
                const float hm0 = 2.f*sigm(s0[r])*sH[row*256 + j0];
                const float hm1 = 2.f*sigm(s1[r])*sH[row*256 + j1];
                unsigned short a,b,c;
                split3(hm0,a,b,c); sA[0][row][100+j0]=a; sA[1][row][100+j0]=b; sA[2][row][100+j0]=c;
                split3(hm1,a,b,c); sA[0][row][100+j1]=a; sA[1][row][100+j1]=b; sA[2][row][100+j1]=c;
            }
        }
        __syncthreads();

        // ---- phase 3: G = [xm|hm]@W (MFMA, 8 tiles/wave) ------------------
        // Product-major, dep-distance-4 accumulators, double-buffered W.
        f32x4 acc[8];
        #pragma unroll
        for (int q = 0; q < 8; ++q) acc[q] = zv;
        {
            bf16x8 WHa0,WHa1,WHa2,WHa3, WMa0,WMa1,WMa2,WMa3, WLa0,WLa1,WLa2,WLa3;
            bf16x8 WHb0,WHb1,WHb2,WHb3, WMb0,WMb1,WMb2,WMb3, WLb0,WLb1,WLb2,WLb3;
            bf16x8 ah, am, al, ah2, am2, al2;
            // prologue: A(ks0), W buffer a = (ks0, tiles 0-3)
            ah = *(const bf16x8*)&sA[0][nn][koff];
            am = *(const bf16x8*)&sA[1][nn][koff];
            al = *(const bf16x8*)&sA[2][nn][koff];
            LDWB(a, 0, koff);
            for (int ks = 0; ks < 12; ++ks) {
                const int ao  = ks*32 + koff;
                const int aon = (ks < 11) ? (ao + 32) : ao;   // clamped
                LDWB(b, 4, ao);         // this ks, tiles 4-7
                MMG(a, 0);              // 24 MFMA tiles 0-3 (buffer a)
                LDWB(a, 0, aon);        // next ks, tiles 0-3
                ah2 = *(const bf16x8*)&sA[0][nn][aon];   // prefetch A(ks+1)
                am2 = *(const bf16x8*)&sA[1][nn][aon];
                al2 = *(const bf16x8*)&sA[2][nn][aon];
                MMG(b, 4);              // 24 MFMA tiles 4-7 (buffer b)
                ah = ah2; am = am2; al = al2;
            }
        }

        // ---- phase 4: register-local cell update; h -> sH/sh3/hout --------
        #pragma unroll
        for (int grp = 0; grp < 2; ++grp) {
            const int j = wv*16 + nn + grp*128;
            #pragma unroll
            for (int r = 0; r < 4; ++r) {
                const int row = m4 + r;
                const float gi = acc[0+grp][r] + bq[0+grp];
                const float gf = acc[2+grp][r] + bq[2+grp];
                const float gg = acc[4+grp][r] + bq[4+grp];
                const float go = acc[6+grp][r] + bq[6+grp];
                const float cv = sigm(gf)*cc[grp*4+r] + sigm(gi)*tanhf(gg);
                cc[grp*4+r] = cv;
                const float hv = sigm(go)*tanhf(cv);
                sH[row*256 + j] = hv;
                unsigned short a,b,c;
                split3(hv,a,b,c);
                sh3[0][row][j] = a; sh3[1][row][j] = b; sh3[2][row][j] = c;
                __builtin_nontemporal_store(hv, &hout[((size_t)t*BB + b0 + row)*HH + j]);
            }
        }
        __syncthreads();
    }
}

// ---------------------------------------------------------------------------
// logits = [hf|hb] @ Wt^T + bt ; argmax (first index on ties) -> out[b][t]
// ---------------------------------------------------------------------------
__global__ __launch_bounds__(256) void logits_kernel(
    const float* __restrict__ hf, const float* __restrict__ hb,
    const float* __restrict__ Wt, const float* __restrict__ bt,
    int* __restrict__ out)
{
    __shared__ float sW[NTAG][2 * HH];
    __shared__ float sb[NTAG];
    const int tid = threadIdx.x;
    for (int i = tid; i < NTAG * 2 * HH; i += 256) (&sW[0][0])[i] = Wt[i];
    if (tid < NTAG) sb[tid] = bt[tid];
    __syncthreads();

    const int pos = blockIdx.x * 256 + tid;
    const int b  = pos & 511;
    const int t0 = pos >> 9;
    const int t1 = t0 + 64;

    float acc0[NTAG], acc1[NTAG];
    #pragma unroll
    for (int n = 0; n < NTAG; ++n) { acc0[n] = sb[n]; acc1[n] = sb[n]; }

    const float* f0 = hf + ((size_t)t0 * BB + b) * HH;
    const float* f1 = hf + ((size_t)t1 * BB + b) * HH;
    for (int k = 0; k < HH; k += 4) {
        const float4 a0 = *(const float4*)(f0 + k);
        const float4 a1 = *(const float4*)(f1 + k);
        #pragma unroll
        for (int n = 0; n < NTAG; ++n) {
            const float4 w = *(const float4*)&sW[n][k];
            acc0[n] += a0.x * w.x + a0.y * w.y + a0.z * w.z + a0.w * w.w;
            acc1[n] += a1.x * w.x + a1.y * w.y + a1.z * w.z + a1.w * w.w;
        }
    }
    const float* g0 = hb + ((size_t)t0 * BB + b) * HH;
    const float* g1 = hb + ((size_t)t1 * BB + b) * HH;
    for (int k = 0; k < HH; k += 4) {
        const float4 a0 = *(const float4*)(g0 + k);
        const float4 a1 = *(const float4*)(g1 + k);
        #pragma unroll
        for (int n = 0; n < NTAG; ++n) {
            const float4 w = *(const float4*)&sW[n][HH + k];
            acc0[n] += a0.x * w.x + a0.y * w.y + a0.z * w.z + a0.w * w.w;
            acc1[n] += a1.x * w.x + a1.y * w.y + a1.z * w.z + a1.w * w.w;
        }
    }

    float b0v = acc0[0]; int i0 = 0;
    float b1v = acc1[0]; int i1 = 0;
    #pragma unroll
    for (int n = 1; n < NTAG; ++n) {
        if (acc0[n] > b0v) { b0v = acc0[n]; i0 = n; }
        if (acc1[n] > b1v) { b1v = acc1[n]; i1 = n; }
    }
    out[b * TT + t0] = i0;
    out[b * TT + t1] = i1;
}

// ---------------------------------------------------------------------------
extern "C" void kernel_launch(void* const* d_in, const int* in_sizes, int n_in,
                              void* d_out, int out_size, void* d_ws, size_t ws_size,
                              hipStream_t stream)
{
    (void)in_sizes; (void)n_in; (void)out_size; (void)ws_size;

    const int*   words = (const int*)  d_in[0];
    const float* embd  = (const float*)d_in[5];
    const float* Wih_f = (const float*)d_in[6];
    const float* Whh_f = (const float*)d_in[7];
    const float* bih_f = (const float*)d_in[8];
    const float* bhh_f = (const float*)d_in[9];
    const float* Q_f   = (const float*)d_in[10];
    const float* R_f   = (const float*)d_in[11];
    const float* Wih_b = (const float*)d_in[12];
    const float* Whh_b = (const float*)d_in[13];
    const float* bih_b = (const float*)d_in[14];
    const float* bhh_b = (const float*)d_in[15];
    const float* Q_b   = (const float*)d_in[16];
    const float* R_b   = (const float*)d_in[17];
    const float* Wt    = (const float*)d_in[18];
    const float* bt    = (const float*)d_in[19];
    int* out = (int*)d_out;

    // workspace layout: hf, hb (fp32), biases, then bf16x3 split arrays (~134 MB)
    float* hf   = (float*)d_ws;
    float* hb   = hf + (size_t)TT * BB * HH;
    float* bP_f = hb + (size_t)TT * BB * HH;
    float* bP_b = bP_f + G4;
    unsigned short* Ws_f = (unsigned short*)(bP_b + G4);
    unsigned short* Qs_f = Ws_f + 3 * (size_t)NW;
    unsigned short* Rs_f = Qs_f + 3 * (size_t)NQ;
    unsigned short* Ws_b = Rs_f + 3 * (size_t)NR;
    unsigned short* Qs_b = Ws_b + 3 * (size_t)NW;
    unsigned short* Rs_b = Qs_b + 3 * (size_t)NQ;

    const int prep_grid = (NW + NQ + NR + G4 + 255) / 256;
    prep8<<<prep_grid, 256, 0, stream>>>(Wih_f, Whh_f, bih_f, bhh_f, Q_f, R_f,
                                         Ws_f, Qs_f, Rs_f, bP_f);
    prep8<<<prep_grid, 256, 0, stream>>>(Wih_b, Whh_b, bih_b, bhh_b, Q_b, R_b,
                                         Ws_b, Qs_b, Rs_b, bP_b);
    lstm12<<<64, 512, 0, stream>>>(words, embd, Qs_f, Rs_f, Ws_f, bP_f,
                                   Qs_b, Rs_b, Ws_b, bP_b, hf, hb);
    logits_kernel<<<128, 256, 0, stream>>>(hf, hb, Wt, bt, out);
}